// Round 10
// baseline (321.067 us; speedup 1.0000x reference)
//
#include <hip/hip_runtime.h>

typedef __bf16 bf16_t;
typedef __attribute__((ext_vector_type(8))) __bf16 bf16x8;
typedef __attribute__((ext_vector_type(4))) float f32x4;

#define MFMA(a,b,c) __builtin_amdgcn_mfma_f32_16x16x32_bf16(a,b,c,0,0,0)

static __device__ __forceinline__ unsigned short f2bfbits(float f){
  unsigned int u = __builtin_bit_cast(unsigned int, f);
  return (unsigned short)((u + 0x7FFFu + ((u >> 16) & 1u)) >> 16);
}
static __device__ __forceinline__ float bits2f(unsigned int b){
  return __builtin_bit_cast(float, b << 16);
}
static __device__ __forceinline__ void gl_lds16(const void* g, void* l){
  __builtin_amdgcn_global_load_lds(
      (const __attribute__((address_space(1))) void*)(g),
      (__attribute__((address_space(3))) void*)(l), 16, 0, 0);
}
static __device__ __forceinline__ void unpack8(uint4 raw, float* f){
  f[0]=bits2f(raw.x&0xFFFFu); f[1]=bits2f(raw.x>>16);
  f[2]=bits2f(raw.y&0xFFFFu); f[3]=bits2f(raw.y>>16);
  f[4]=bits2f(raw.z&0xFFFFu); f[5]=bits2f(raw.z>>16);
  f[6]=bits2f(raw.w&0xFFFFu); f[7]=bits2f(raw.w>>16);
}

// ---------------- fp32 -> bf16 convert, all three inputs in one launch ----------------
__global__ __launch_bounds__(256) void cvt_all(const float* __restrict__ x,
                                               const float* __restrict__ wqkv,
                                               const float* __restrict__ wout,
                                               unsigned short* __restrict__ xb,
                                               unsigned short* __restrict__ wqb,
                                               unsigned short* __restrict__ wob){
  const long n4 = 5242880;   // 4194304 (x) + 786432 (wqkv) + 262144 (wout) float4 groups
  const long stride = (long)gridDim.x * 256;
  for (long i = (long)blockIdx.x * 256 + threadIdx.x; i < n4; i += stride){
    const float* in; unsigned short* out; long e;
    if (i < 4194304){ in = x; out = xb; e = i; }
    else if (i < 4980736){ in = wqkv; out = wqb; e = i - 4194304; }
    else { in = wout; out = wob; e = i - 4980736; }
    float4 v = *(const float4*)(in + e * 4);
    unsigned long long pack = (unsigned long long)f2bfbits(v.x)
      | ((unsigned long long)f2bfbits(v.y) << 16)
      | ((unsigned long long)f2bfbits(v.z) << 32)
      | ((unsigned long long)f2bfbits(v.w) << 48);
    *(unsigned long long*)(out + e * 4) = pack;
  }
}

// ---- 256x256 GEMM, B^T input; BK=64 dbuf, 4-phase/K-tile (R8, best-of-family) ----
template<int MODE>
__global__ __launch_bounds__(512, 2) void gemm256(
    const unsigned short* __restrict__ A, const unsigned short* __restrict__ B,
    const int K, const int nbx,
    unsigned short* __restrict__ oq, unsigned short* __restrict__ ok2, unsigned short* __restrict__ ov,
    float* __restrict__ outp, const float* __restrict__ bias)
{
  __shared__ char lds[131072];
  const int t = threadIdx.x;
  const int lane = t & 63, wid = t >> 6;
  const int wr = wid >> 2, wc = wid & 3;
  const int r16 = lane & 15, g = lane >> 4;

  const int nb = gridDim.x, cpx = nb >> 3;
  const int lin = (blockIdx.x & 7) * cpx + (blockIdx.x >> 3);
  const int by = lin / nbx, bx = lin - by * nbx;
  const long row0 = (long)by * 256, col0 = (long)bx * 256;

  const unsigned short* gA[4]; const unsigned short* gB[4];
  int ldsoff[4];
  #pragma unroll
  for (int r2 = 0; r2 < 4; ++r2){
    const int flat = r2*512 + t;
    const int row = flat >> 3, slot = flat & 7;
    const int slotg = slot ^ (row & 7);
    gA[r2] = A + (row0 + row) * K + slotg*8;
    gB[r2] = B + (col0 + row) * K + slotg*8;
    ldsoff[r2] = (r2*512 + wid*64) * 16;
  }

  f32x4 acc[8][4];
  #pragma unroll
  for (int m = 0; m < 8; ++m)
    #pragma unroll
    for (int n = 0; n < 4; ++n)
      acc[m][n] = (f32x4){0.f, 0.f, 0.f, 0.f};

  const int nk = K >> 6;

  #define SA(tt, r) gl_lds16(gA[r] + (tt)*64, lds + ((tt)&1)*65536 + ldsoff[r])
  #define SB(tt, r) gl_lds16(gB[r] + (tt)*64, lds + ((tt)&1)*65536 + 32768 + ldsoff[r])

  SA(0,0); SA(0,2); SB(0,0); SB(0,1); SB(0,2); SB(0,3); SA(0,1); SA(0,3);
  asm volatile("s_waitcnt vmcnt(2)" ::: "memory");
  __builtin_amdgcn_s_barrier();

  for (int kt = 0; kt < nk; ++kt){
    char* ldsA = lds + (kt & 1)*65536;
    char* ldsB = ldsA + 32768;
    const bool more = (kt + 1 < nk);
    bf16x8 bfrag[4][2];

    // ph0
    {
      #pragma unroll
      for (int n = 0; n < 4; ++n)
        #pragma unroll
        for (int kk = 0; kk < 2; ++kk){
          const int row = wc*64 + n*16 + r16;
          bfrag[n][kk] = *(const bf16x8*)(ldsB + row*128 + (((kk*4 + g) ^ (row & 7)) * 16));
        }
      bf16x8 afr[2][2];
      #pragma unroll
      for (int mi = 0; mi < 2; ++mi)
        #pragma unroll
        for (int kk = 0; kk < 2; ++kk){
          const int row = wr*128 + mi*16 + r16;
          afr[mi][kk] = *(const bf16x8*)(ldsA + row*128 + (((kk*4 + g) ^ (row & 7)) * 16));
        }
      if (more){ SA(kt+1,0); SA(kt+1,2); }
      __builtin_amdgcn_s_barrier();
      asm volatile("s_waitcnt lgkmcnt(0)" ::: "memory");
      __builtin_amdgcn_sched_barrier(0);
      __builtin_amdgcn_s_setprio(1);
      #pragma unroll
      for (int mi = 0; mi < 2; ++mi)
        #pragma unroll
        for (int n = 0; n < 4; ++n)
          #pragma unroll
          for (int kk = 0; kk < 2; ++kk)
            acc[mi][n] = MFMA(afr[mi][kk], bfrag[n][kk], acc[mi][n]);
      __builtin_amdgcn_s_setprio(0);
      __builtin_amdgcn_s_barrier();
    }
    // ph1
    {
      bf16x8 afr[2][2];
      #pragma unroll
      for (int mi = 0; mi < 2; ++mi)
        #pragma unroll
        for (int kk = 0; kk < 2; ++kk){
          const int row = wr*128 + (2+mi)*16 + r16;
          afr[mi][kk] = *(const bf16x8*)(ldsA + row*128 + (((kk*4 + g) ^ (row & 7)) * 16));
        }
      if (more){
        SB(kt+1,0); SB(kt+1,1);
        asm volatile("s_waitcnt vmcnt(4)" ::: "memory");
      } else {
        asm volatile("s_waitcnt vmcnt(0)" ::: "memory");
      }
      __builtin_amdgcn_s_barrier();
      asm volatile("s_waitcnt lgkmcnt(0)" ::: "memory");
      __builtin_amdgcn_sched_barrier(0);
      __builtin_amdgcn_s_setprio(1);
      #pragma unroll
      for (int mi = 0; mi < 2; ++mi)
        #pragma unroll
        for (int n = 0; n < 4; ++n)
          #pragma unroll
          for (int kk = 0; kk < 2; ++kk)
            acc[2+mi][n] = MFMA(afr[mi][kk], bfrag[n][kk], acc[2+mi][n]);
      __builtin_amdgcn_s_setprio(0);
      __builtin_amdgcn_s_barrier();
    }
    // ph2
    {
      bf16x8 afr[2][2];
      #pragma unroll
      for (int mi = 0; mi < 2; ++mi)
        #pragma unroll
        for (int kk = 0; kk < 2; ++kk){
          const int row = wr*128 + (4+mi)*16 + r16;
          afr[mi][kk] = *(const bf16x8*)(ldsA + row*128 + (((kk*4 + g) ^ (row & 7)) * 16));
        }
      if (more){ SB(kt+1,2); SB(kt+1,3); }
      __builtin_amdgcn_s_barrier();
      asm volatile("s_waitcnt lgkmcnt(0)" ::: "memory");
      __builtin_amdgcn_sched_barrier(0);
      __builtin_amdgcn_s_setprio(1);
      #pragma unroll
      for (int mi = 0; mi < 2; ++mi)
        #pragma unroll
        for (int n = 0; n < 4; ++n)
          #pragma unroll
          for (int kk = 0; kk < 2; ++kk)
            acc[4+mi][n] = MFMA(afr[mi][kk], bfrag[n][kk], acc[4+mi][n]);
      __builtin_amdgcn_s_setprio(0);
      __builtin_amdgcn_s_barrier();
    }
    // ph3
    {
      bf16x8 afr[2][2];
      #pragma unroll
      for (int mi = 0; mi < 2; ++mi)
        #pragma unroll
        for (int kk = 0; kk < 2; ++kk){
          const int row = wr*128 + (6+mi)*16 + r16;
          afr[mi][kk] = *(const bf16x8*)(ldsA + row*128 + (((kk*4 + g) ^ (row & 7)) * 16));
        }
      if (more){
        SA(kt+1,1); SA(kt+1,3);
        asm volatile("s_waitcnt vmcnt(2)" ::: "memory");
      }
      __builtin_amdgcn_s_barrier();
      asm volatile("s_waitcnt lgkmcnt(0)" ::: "memory");
      __builtin_amdgcn_sched_barrier(0);
      __builtin_amdgcn_s_setprio(1);
      #pragma unroll
      for (int mi = 0; mi < 2; ++mi)
        #pragma unroll
        for (int n = 0; n < 4; ++n)
          #pragma unroll
          for (int kk = 0; kk < 2; ++kk)
            acc[6+mi][n] = MFMA(afr[mi][kk], bfrag[n][kk], acc[6+mi][n]);
      __builtin_amdgcn_s_setprio(0);
      __builtin_amdgcn_s_barrier();
    }
  }
  #undef SA
  #undef SB

  if (MODE == 0){
    __syncthreads();
    const int which = (int)(col0 >> 10);
    const int h = (int)((col0 & 1023) >> 6) + wc;
    const float sc = (which == 0) ? 0.125f : 1.0f;
    unsigned short* st = (unsigned short*)lds + wid*8192;
    #pragma unroll
    for (int pass = 0; pass < 2; ++pass){
      #pragma unroll
      for (int mm = 0; mm < 4; ++mm)
        #pragma unroll
        for (int n = 0; n < 4; ++n)
          #pragma unroll
          for (int q2 = 0; q2 < 4; ++q2)
            st[(mm*16 + g*4 + q2)*72 + n*16 + r16] = f2bfbits(acc[pass*4 + mm][n][q2] * sc);
      const long prow0 = row0 + wr*128 + pass*64;
      if (which < 2){
        unsigned short* dst = (which == 0) ? oq : ok2;
        #pragma unroll
        for (int rd = 0; rd < 8; ++rd){
          const int rl = rd*8 + (lane >> 3);
          const int gr = lane & 7;
          uint4 v = *(const uint4*)&st[rl*72 + gr*8];
          const long ii = prow0 + rl;
          const int b_ = (int)(ii >> 12), pos = (int)(ii & 4095);
          *(uint4*)&dst[(((long)b_*16 + h)*4096 + pos)*64 + gr*8] = v;
        }
      } else {
        #pragma unroll
        for (int rd = 0; rd < 8; ++rd){
          const int blk = rd >> 1;
          const int d = (rd & 1)*32 + (lane >> 1);
          const int kkh = lane & 1;
          unsigned short tmp[8];
          #pragma unroll
          for (int j = 0; j < 8; ++j)
            tmp[j] = st[(blk*16 + kkh*8 + j)*72 + d];
          uint4 v;
          v.x = (unsigned int)tmp[0] | ((unsigned int)tmp[1] << 16);
          v.y = (unsigned int)tmp[2] | ((unsigned int)tmp[3] << 16);
          v.z = (unsigned int)tmp[4] | ((unsigned int)tmp[5] << 16);
          v.w = (unsigned int)tmp[6] | ((unsigned int)tmp[7] << 16);
          const long posblk = (prow0 >> 4) + blk;
          const int b_ = (int)(posblk >> 8), blkg = (int)(posblk & 255);
          *(uint4*)&ov[(((long)b_*16 + h)*256 + blkg)*1024 + d*16 + kkh*8] = v;
        }
      }
      __builtin_amdgcn_sched_barrier(0);
    }
  } else {
    #pragma unroll
    for (int n = 0; n < 4; ++n){
      const long j = col0 + wc*64 + n*16 + r16;
      const float bi = bias[j];
      #pragma unroll
      for (int m = 0; m < 8; ++m){
        const long ib = row0 + wr*128 + m*16 + g*4;
        #pragma unroll
        for (int q2 = 0; q2 < 4; ++q2)
          outp[(ib + q2)*1024 + j] = acc[m][n][q2] + bi;
      }
    }
  }
}

// ---------------- hierarchical coarsen, half-compacted outputs ----------------
__global__ __launch_bounds__(256) void coarsen(
    const unsigned short* __restrict__ q0, const unsigned short* __restrict__ k0,
    const unsigned short* __restrict__ vt0,
    unsigned short* __restrict__ qch, unsigned short* __restrict__ kch,
    unsigned short* __restrict__ vch)
{
  __shared__ float Abuf[128*65];
  __shared__ float Bbuf[64*65];
  const int t = threadIdx.x;
  const int chunk = blockIdx.x;
  const int bh = blockIdx.y;
  const int arr = blockIdx.z;
  if (arr < 2){
    const unsigned short* src = (arr == 0) ? q0 : k0;
    const long sbase = ((long)bh*4096 + (long)chunk*128) * 64;
    #pragma unroll
    for (int it = 0; it < 4; ++it){
      const int idx = it*2048 + t*8;
      uint4 raw = *(const uint4*)(src + sbase + idx);
      float f[8]; unpack8(raw, f);
      const int rowb = idx >> 6, colb = idx & 63;
      #pragma unroll
      for (int j = 0; j < 8; ++j) Abuf[rowb*65 + colb + j] = f[j];
    }
  } else {
    const long sbase = ((long)bh*256 + (long)chunk*8) * 1024;
    #pragma unroll
    for (int it = 0; it < 4; ++it){
      const int flat = it*2048 + t*8;
      const int blk = flat >> 10, rem = flat & 1023;
      const int d = rem >> 4, kk0 = rem & 15;
      uint4 raw = *(const uint4*)(vt0 + sbase + flat);
      float f[8]; unpack8(raw, f);
      #pragma unroll
      for (int j = 0; j < 8; ++j) Abuf[(blk*16 + kk0 + j)*65 + d] = f[j];
    }
  }
  __syncthreads();
  float* cur = Abuf; float* nxt = Bbuf;
  int rows = 128;
  const int Spre[8] = {0, 0, 1024, 1536, 1792, 1920, 1984, 2016};
  for (int l = 1; l <= 7; ++l){
    rows >>= 1;
    const int P = 2048 >> l;
    const long base = (long)Spre[l] * 4096;
    for (int e = t; e < rows*64; e += 256){
      const int p = e >> 6, d = e & 63;
      const float a = cur[(2*p)*65 + d], b2 = cur[(2*p + 1)*65 + d];
      const float val = (arr == 2) ? (a + b2) : 0.5f*(a + b2);
      nxt[p*65 + d] = val;
      const int pl = chunk*rows + p;
      const int cb = pl >> 4, ci = cb >> 1;
      if (arr == 0){
        if (cb & 1) qch[base + ((long)bh*P + ci*16 + (pl & 15))*64 + d] = f2bfbits(val);
      } else if (arr == 1){
        if (!(cb & 1)) kch[base + ((long)bh*P + ci*16 + (pl & 15))*64 + d] = f2bfbits(val);
      } else if (rows < 16){
        if (!(cb & 1)) vch[base + (long)bh*P*64 + ci*1024 + d*16 + (pl & 15)] = f2bfbits(val);
      }
    }
    __syncthreads();
    if (arr == 2 && rows >= 16){
      const int nblk = rows >> 4;
      for (int oe = t; oe < nblk*1024; oe += 256){
        const int bl = oe >> 10, rem = oe & 1023;
        const int cb = chunk*nblk + bl;
        if (cb & 1) continue;
        const int d = rem >> 4, kk = rem & 15;
        vch[base + (long)bh*P*64 + (long)(cb>>1)*1024 + rem] = f2bfbits(nxt[(bl*16 + kk)*65 + d]);
      }
    }
    float* tmp = cur; cur = nxt; nxt = tmp;
  }
}

// ---- one level-l attention job: coarse block cb (odd) attends cb-1; scatter into block accs ----
static __device__ __forceinline__ void attn_level(
    int l, int cb, int row_lo, int row_n, int bh,
    const unsigned short* __restrict__ qch, const unsigned short* __restrict__ kch,
    const unsigned short* __restrict__ vch,
    float* accs, float* denoms, int lane)
{
  const int r = lane & 15, g = lane >> 4;
  const int Spre[8] = {0, 0, 1024, 1536, 1792, 1920, 1984, 2016};
  const int ci = cb >> 1;
  const int P = 2048 >> l;
  const long base = (long)Spre[l] * 4096;
  const long qb_base = base + ((long)bh*P + ci*16) * 64;
  const long kv_base = base + (long)bh*P*64 + (long)ci*1024;

  const bf16x8 ka0 = *(const bf16x8*)(kch + qb_base + r*64 + g*8);
  const bf16x8 ka1 = *(const bf16x8*)(kch + qb_base + r*64 + g*8 + 32);
  const bf16x8 qb0 = *(const bf16x8*)(qch + qb_base + r*64 + g*8);
  const bf16x8 qb1 = *(const bf16x8*)(qch + qb_base + r*64 + g*8 + 32);
  f32x4 s = {0.f,0.f,0.f,0.f};
  s = MFMA(ka0, qb0, s);
  s = MFMA(ka1, qb1, s);

  float p[4];
  float mx = fmaxf(fmaxf(s[0], s[1]), fmaxf(s[2], s[3]));
  mx = fmaxf(mx, __shfl_xor(mx, 16));
  mx = fmaxf(mx, __shfl_xor(mx, 32));
  float rs = 0.f;
  #pragma unroll
  for (int j = 0; j < 4; ++j){ p[j] = __expf(s[j] - mx); rs += p[j]; }
  rs += __shfl_xor(rs, 16);
  rs += __shfl_xor(rs, 32);

  float x16[4], x32[4], x48[4];
  #pragma unroll
  for (int j = 0; j < 4; ++j){
    x16[j] = __shfl_xor(p[j], 16);
    x32[j] = __shfl_xor(p[j], 32);
    x48[j] = __shfl_xor(p[j], 48);
  }
  bf16x8 af;
  #pragma unroll
  for (int j = 0; j < 4; ++j){
    const float lo2 = (g == 0) ? p[j]   : (g == 1) ? x48[j] : 0.f;
    const float hi2 = (g == 0) ? x16[j] : (g == 1) ? x32[j] : 0.f;
    af[j]   = (bf16_t)lo2;
    af[j+4] = (bf16_t)hi2;
  }
  #pragma unroll
  for (int nb = 0; nb < 4; ++nb){
    bf16x8 bv;
    #pragma unroll
    for (int j = 0; j < 8; ++j) bv[j] = (bf16_t)0.f;
    if (g < 2) bv = *(const bf16x8*)(vch + kv_base + (nb*16 + r)*16 + g*8);
    f32x4 y = {0.f,0.f,0.f,0.f};
    y = MFMA(af, bv, y);
    #pragma unroll
    for (int q2 = 0; q2 < 4; ++q2){
      const int row = g*4 + q2;
      if (row >= row_lo && row < row_lo + row_n){
        const int pos = (((cb*16 + row + 1) << l) - 1) & 63;   // proven in-block
        atomicAdd(&accs[pos*64 + nb*16 + r], y[q2]);
      }
    }
  }
  if (g == 0 && r >= row_lo && r < row_lo + row_n){
    const int pos = (((cb*16 + r + 1) << l) - 1) & 63;
    atomicAdd(&denoms[pos], rs);
  }
}

// ------- fused all-level attention: block-cooperative, block = 64 positions (4 waves) -------
// l0: per-wave (disjoint writes). Levels 1-7: one job per block per level, assigned to a
// fixed wave, accumulated via LDS atomicAdd (positions collide across levels).
__global__ __launch_bounds__(256) void attn_fused(
    const unsigned short* __restrict__ q0, const unsigned short* __restrict__ k0,
    const unsigned short* __restrict__ vt0,
    const unsigned short* __restrict__ qch, const unsigned short* __restrict__ kch,
    const unsigned short* __restrict__ vch,
    unsigned short* __restrict__ ybf)
{
  const int t = threadIdx.x;
  const int lane = t & 63;
  const int w = t >> 6;
  const int b = blockIdx.x;            // 0..63 (64-position group)
  const int bh = blockIdx.y;           // 0..63
  const int b_ = bh >> 4, h = bh & 15;
  const int r = lane & 15, g = lane >> 4;
  __shared__ float accs[64*64];
  __shared__ float denoms[64];

  // ---- level 0: causal diagonal 16x16, one wave per 16-row sub-block ----
  {
    const int B0 = b*4 + w;
    const long base = ((long)bh*4096 + (long)B0*16) * 64;
    const bf16x8 ka0 = *(const bf16x8*)(k0 + base + r*64 + g*8);
    const bf16x8 ka1 = *(const bf16x8*)(k0 + base + r*64 + g*8 + 32);
    const bf16x8 qb0 = *(const bf16x8*)(q0 + base + r*64 + g*8);
    const bf16x8 qb1 = *(const bf16x8*)(q0 + base + r*64 + g*8 + 32);
    f32x4 s = {0.f,0.f,0.f,0.f};
    s = MFMA(ka0, qb0, s);
    s = MFMA(ka1, qb1, s);          // lane holds S[q=r][k=g*4+j]

    float p[4];
    float mx = -3.402823466e38f;
    #pragma unroll
    for (int j = 0; j < 4; ++j){
      const int c = g*4 + j;
      p[j] = (c <= r) ? s[j] : -3.402823466e38f;
      mx = fmaxf(mx, p[j]);
    }
    mx = fmaxf(mx, __shfl_xor(mx, 16));
    mx = fmaxf(mx, __shfl_xor(mx, 32));
    float rs = 0.f;
    #pragma unroll
    for (int j = 0; j < 4; ++j){
      const int c = g*4 + j;
      p[j] = (c <= r) ? __expf(p[j] - mx) : 0.f;
      rs += p[j];
    }
    rs += __shfl_xor(rs, 16);
    rs += __shfl_xor(rs, 32);

    float x16[4], x32[4], x48[4];
    #pragma unroll
    for (int j = 0; j < 4; ++j){
      x16[j] = __shfl_xor(p[j], 16);
      x32[j] = __shfl_xor(p[j], 32);
      x48[j] = __shfl_xor(p[j], 48);
    }
    bf16x8 af;
    #pragma unroll
    for (int j = 0; j < 4; ++j){
      const float lo = (g == 0) ? p[j]   : (g == 1) ? x48[j] : 0.f;
      const float hi = (g == 0) ? x16[j] : (g == 1) ? x32[j] : 0.f;
      af[j]   = (bf16_t)lo;
      af[j+4] = (bf16_t)hi;
    }
    const unsigned short* vt = vt0 + ((long)bh*256 + B0) * 1024;
    #pragma unroll
    for (int nb = 0; nb < 4; ++nb){
      bf16x8 bv;
      #pragma unroll
      for (int j = 0; j < 8; ++j) bv[j] = (bf16_t)0.f;
      if (g < 2) bv = *(const bf16x8*)(vt + (nb*16 + r)*16 + g*8);
      f32x4 y = {0.f,0.f,0.f,0.f};
      y = MFMA(af, bv, y);
      #pragma unroll
      for (int q2 = 0; q2 < 4; ++q2)
        accs[(w*16 + g*4 + q2)*64 + nb*16 + r] = y[q2];
    }
    if (g == 0) denoms[w*16 + r] = rs;
  }
  __syncthreads();

  // ---- levels 1..7: one job per firing level, fixed wave assignment ----
  if (w == 0){
    attn_level(1, 2*b + 1, 0, 16, bh, qch, kch, vch, accs, denoms, lane);
    if ((b >> 3) & 1) attn_level(5, b >> 3, (2*b) & 15, 2, bh, qch, kch, vch, accs, denoms, lane);
  } else if (w == 1){
    if (b & 1)        attn_level(2, b, 0, 16, bh, qch, kch, vch, accs, denoms, lane);
    if ((b >> 4) & 1) attn_level(6, b >> 4, b & 15, 1, bh, qch, kch, vch, accs, denoms, lane);
  } else if (w == 2){
    if (b & 2)        attn_level(3, b >> 1, 8*(b & 1), 8, bh, qch, kch, vch, accs, denoms, lane);
    if ((b & 1) && (((b - 1) >> 5) & 1))
                      attn_level(7, (b - 1) >> 5, ((b - 1) >> 1) & 15, 1, bh, qch, kch, vch, accs, denoms, lane);
  } else {
    if (b & 4)        attn_level(4, b >> 2, 4*(b & 3), 4, bh, qch, kch, vch, accs, denoms, lane);
  }
  __syncthreads();

  // ---- normalize + write bf16 (256 threads over 64 rows) ----
  const int row = t >> 2, d0 = (t & 3) * 16;
  const float inv = 1.f / (denoms[row] + 1e-8f);
  unsigned int wv[8];
  #pragma unroll
  for (int j2 = 0; j2 < 8; ++j2){
    const float a = accs[row*64 + d0 + 2*j2]      * inv;
    const float b2 = accs[row*64 + d0 + 2*j2 + 1] * inv;
    wv[j2] = (unsigned int)f2bfbits(a) | ((unsigned int)f2bfbits(b2) << 16);
  }
  uint4* dst = (uint4*)(ybf + ((long)b_*4096 + b*64 + row)*1024 + h*64 + d0);
  dst[0] = make_uint4(wv[0], wv[1], wv[2], wv[3]);
  dst[1] = make_uint4(wv[4], wv[5], wv[6], wv[7]);
}

extern "C" void kernel_launch(void* const* d_in, const int* in_sizes, int n_in,
                              void* d_out, int out_size, void* d_ws, size_t ws_size,
                              hipStream_t stream){
  const float* x    = (const float*)d_in[0];
  const float* wqkv = (const float*)d_in[1];
  const float* wout = (const float*)d_in[2];
  const float* bout = (const float*)d_in[3];
  float* out = (float*)d_out;
  char* ws = (char*)d_ws;

  // workspace layout (total 192,544,768 B):
  unsigned short* wqb = (unsigned short*)(ws + 0L);            //  6.29 MB
  unsigned short* wob = (unsigned short*)(ws + 6291456L);      //  2.10 MB
  unsigned short* xb  = (unsigned short*)(ws + 8388608L);      // 33.55 MB (reused as ybf)
  unsigned short* q0  = (unsigned short*)(ws + 41943040L);     // 33.55 MB [bh][pos][64]
  unsigned short* k0  = (unsigned short*)(ws + 75497472L);     // 33.55 MB [bh][pos][64]
  unsigned short* vt0 = (unsigned short*)(ws + 109051904L);    // 33.55 MB [bh][blk][64][16]
  unsigned short* qch = (unsigned short*)(ws + 142606336L);    // 16.65 MB odd-block coarse q
  unsigned short* kch = (unsigned short*)(ws + 159252480L);    // 16.65 MB even-block coarse k
  unsigned short* vch = (unsigned short*)(ws + 175898624L);    // 16.65 MB even-block coarse v^T
  unsigned short* ybf = xb;

  cvt_all<<<2048, 256, 0, stream>>>(x, wqkv, wout, xb, wqb, wob);

  gemm256<0><<<768, 512, 0, stream>>>(xb, wqb, 1024, 12, q0, k0, vt0, nullptr, nullptr);
  coarsen<<<dim3(32,64,3), 256, 0, stream>>>(q0, k0, vt0, qch, kch, vch);
  attn_fused<<<dim3(64,64), 256, 0, stream>>>(q0, k0, vt0, qch, kch, vch, ybf);
  gemm256<1><<<256, 512, 0, stream>>>(ybf, wob, 1024, 4, nullptr, nullptr, nullptr, out, bout);
}

// Round 11
// 295.845 us; speedup vs baseline: 1.0853x; 1.0853x over previous
//
#include <hip/hip_runtime.h>

typedef __bf16 bf16_t;
typedef __attribute__((ext_vector_type(8))) __bf16 bf16x8;
typedef __attribute__((ext_vector_type(4))) float f32x4;

#define MFMA(a,b,c) __builtin_amdgcn_mfma_f32_16x16x32_bf16(a,b,c,0,0,0)

static __device__ __forceinline__ unsigned short f2bfbits(float f){
  unsigned int u = __builtin_bit_cast(unsigned int, f);
  return (unsigned short)((u + 0x7FFFu + ((u >> 16) & 1u)) >> 16);
}
static __device__ __forceinline__ float bits2f(unsigned int b){
  return __builtin_bit_cast(float, b << 16);
}
static __device__ __forceinline__ void gl_lds16(const void* g, void* l){
  __builtin_amdgcn_global_load_lds(
      (const __attribute__((address_space(1))) void*)(g),
      (__attribute__((address_space(3))) void*)(l), 16, 0, 0);
}
static __device__ __forceinline__ void unpack8(uint4 raw, float* f){
  f[0]=bits2f(raw.x&0xFFFFu); f[1]=bits2f(raw.x>>16);
  f[2]=bits2f(raw.y&0xFFFFu); f[3]=bits2f(raw.y>>16);
  f[4]=bits2f(raw.z&0xFFFFu); f[5]=bits2f(raw.z>>16);
  f[6]=bits2f(raw.w&0xFFFFu); f[7]=bits2f(raw.w>>16);
}

// ---------------- fp32 -> bf16 convert, all three inputs in one launch ----------------
__global__ __launch_bounds__(256) void cvt_all(const float* __restrict__ x,
                                               const float* __restrict__ wqkv,
                                               const float* __restrict__ wout,
                                               unsigned short* __restrict__ xb,
                                               unsigned short* __restrict__ wqb,
                                               unsigned short* __restrict__ wob){
  const long n4 = 5242880;   // 4194304 (x) + 786432 (wqkv) + 262144 (wout) float4 groups
  const long stride = (long)gridDim.x * 256;
  for (long i = (long)blockIdx.x * 256 + threadIdx.x; i < n4; i += stride){
    const float* in; unsigned short* out; long e;
    if (i < 4194304){ in = x; out = xb; e = i; }
    else if (i < 4980736){ in = wqkv; out = wqb; e = i - 4194304; }
    else { in = wout; out = wob; e = i - 4980736; }
    float4 v = *(const float4*)(in + e * 4);
    unsigned long long pack = (unsigned long long)f2bfbits(v.x)
      | ((unsigned long long)f2bfbits(v.y) << 16)
      | ((unsigned long long)f2bfbits(v.z) << 32)
      | ((unsigned long long)f2bfbits(v.w) << 48);
    *(unsigned long long*)(out + e * 4) = pack;
  }
}

// ---- 256x256 GEMM, B^T input; BK=64 dbuf, 4-phase/K-tile (R8, best-of-family) ----
// MODE 0: full-line bf16 scatter epilogue (LDS bounce). MODE 1: C+bias -> fp32, full-line
// epilogue via [16][68] f32 LDS bounce (kills MODE-1 RFO).
template<int MODE>
__global__ __launch_bounds__(512, 2) void gemm256(
    const unsigned short* __restrict__ A, const unsigned short* __restrict__ B,
    const int K, const int nbx,
    unsigned short* __restrict__ oq, unsigned short* __restrict__ ok2, unsigned short* __restrict__ ov,
    float* __restrict__ outp, const float* __restrict__ bias)
{
  __shared__ char lds[131072];
  const int t = threadIdx.x;
  const int lane = t & 63, wid = t >> 6;
  const int wr = wid >> 2, wc = wid & 3;
  const int r16 = lane & 15, g = lane >> 4;

  const int nb = gridDim.x, cpx = nb >> 3;
  const int lin = (blockIdx.x & 7) * cpx + (blockIdx.x >> 3);
  const int by = lin / nbx, bx = lin - by * nbx;
  const long row0 = (long)by * 256, col0 = (long)bx * 256;

  const unsigned short* gA[4]; const unsigned short* gB[4];
  int ldsoff[4];
  #pragma unroll
  for (int r2 = 0; r2 < 4; ++r2){
    const int flat = r2*512 + t;
    const int row = flat >> 3, slot = flat & 7;
    const int slotg = slot ^ (row & 7);
    gA[r2] = A + (row0 + row) * K + slotg*8;
    gB[r2] = B + (col0 + row) * K + slotg*8;
    ldsoff[r2] = (r2*512 + wid*64) * 16;
  }

  f32x4 acc[8][4];
  #pragma unroll
  for (int m = 0; m < 8; ++m)
    #pragma unroll
    for (int n = 0; n < 4; ++n)
      acc[m][n] = (f32x4){0.f, 0.f, 0.f, 0.f};

  const int nk = K >> 6;

  #define SA(tt, r) gl_lds16(gA[r] + (tt)*64, lds + ((tt)&1)*65536 + ldsoff[r])
  #define SB(tt, r) gl_lds16(gB[r] + (tt)*64, lds + ((tt)&1)*65536 + 32768 + ldsoff[r])

  SA(0,0); SA(0,2); SB(0,0); SB(0,1); SB(0,2); SB(0,3); SA(0,1); SA(0,3);
  asm volatile("s_waitcnt vmcnt(2)" ::: "memory");
  __builtin_amdgcn_s_barrier();

  for (int kt = 0; kt < nk; ++kt){
    char* ldsA = lds + (kt & 1)*65536;
    char* ldsB = ldsA + 32768;
    const bool more = (kt + 1 < nk);
    bf16x8 bfrag[4][2];

    // ph0
    {
      #pragma unroll
      for (int n = 0; n < 4; ++n)
        #pragma unroll
        for (int kk = 0; kk < 2; ++kk){
          const int row = wc*64 + n*16 + r16;
          bfrag[n][kk] = *(const bf16x8*)(ldsB + row*128 + (((kk*4 + g) ^ (row & 7)) * 16));
        }
      bf16x8 afr[2][2];
      #pragma unroll
      for (int mi = 0; mi < 2; ++mi)
        #pragma unroll
        for (int kk = 0; kk < 2; ++kk){
          const int row = wr*128 + mi*16 + r16;
          afr[mi][kk] = *(const bf16x8*)(ldsA + row*128 + (((kk*4 + g) ^ (row & 7)) * 16));
        }
      if (more){ SA(kt+1,0); SA(kt+1,2); }
      __builtin_amdgcn_s_barrier();
      asm volatile("s_waitcnt lgkmcnt(0)" ::: "memory");
      __builtin_amdgcn_sched_barrier(0);
      __builtin_amdgcn_s_setprio(1);
      #pragma unroll
      for (int mi = 0; mi < 2; ++mi)
        #pragma unroll
        for (int n = 0; n < 4; ++n)
          #pragma unroll
          for (int kk = 0; kk < 2; ++kk)
            acc[mi][n] = MFMA(afr[mi][kk], bfrag[n][kk], acc[mi][n]);
      __builtin_amdgcn_s_setprio(0);
      __builtin_amdgcn_s_barrier();
    }
    // ph1
    {
      bf16x8 afr[2][2];
      #pragma unroll
      for (int mi = 0; mi < 2; ++mi)
        #pragma unroll
        for (int kk = 0; kk < 2; ++kk){
          const int row = wr*128 + (2+mi)*16 + r16;
          afr[mi][kk] = *(const bf16x8*)(ldsA + row*128 + (((kk*4 + g) ^ (row & 7)) * 16));
        }
      if (more){
        SB(kt+1,0); SB(kt+1,1);
        asm volatile("s_waitcnt vmcnt(4)" ::: "memory");
      } else {
        asm volatile("s_waitcnt vmcnt(0)" ::: "memory");
      }
      __builtin_amdgcn_s_barrier();
      asm volatile("s_waitcnt lgkmcnt(0)" ::: "memory");
      __builtin_amdgcn_sched_barrier(0);
      __builtin_amdgcn_s_setprio(1);
      #pragma unroll
      for (int mi = 0; mi < 2; ++mi)
        #pragma unroll
        for (int n = 0; n < 4; ++n)
          #pragma unroll
          for (int kk = 0; kk < 2; ++kk)
            acc[2+mi][n] = MFMA(afr[mi][kk], bfrag[n][kk], acc[2+mi][n]);
      __builtin_amdgcn_s_setprio(0);
      __builtin_amdgcn_s_barrier();
    }
    // ph2
    {
      bf16x8 afr[2][2];
      #pragma unroll
      for (int mi = 0; mi < 2; ++mi)
        #pragma unroll
        for (int kk = 0; kk < 2; ++kk){
          const int row = wr*128 + (4+mi)*16 + r16;
          afr[mi][kk] = *(const bf16x8*)(ldsA + row*128 + (((kk*4 + g) ^ (row & 7)) * 16));
        }
      if (more){ SB(kt+1,2); SB(kt+1,3); }
      __builtin_amdgcn_s_barrier();
      asm volatile("s_waitcnt lgkmcnt(0)" ::: "memory");
      __builtin_amdgcn_sched_barrier(0);
      __builtin_amdgcn_s_setprio(1);
      #pragma unroll
      for (int mi = 0; mi < 2; ++mi)
        #pragma unroll
        for (int n = 0; n < 4; ++n)
          #pragma unroll
          for (int kk = 0; kk < 2; ++kk)
            acc[4+mi][n] = MFMA(afr[mi][kk], bfrag[n][kk], acc[4+mi][n]);
      __builtin_amdgcn_s_setprio(0);
      __builtin_amdgcn_s_barrier();
    }
    // ph3
    {
      bf16x8 afr[2][2];
      #pragma unroll
      for (int mi = 0; mi < 2; ++mi)
        #pragma unroll
        for (int kk = 0; kk < 2; ++kk){
          const int row = wr*128 + (6+mi)*16 + r16;
          afr[mi][kk] = *(const bf16x8*)(ldsA + row*128 + (((kk*4 + g) ^ (row & 7)) * 16));
        }
      if (more){
        SA(kt+1,1); SA(kt+1,3);
        asm volatile("s_waitcnt vmcnt(2)" ::: "memory");
      }
      __builtin_amdgcn_s_barrier();
      asm volatile("s_waitcnt lgkmcnt(0)" ::: "memory");
      __builtin_amdgcn_sched_barrier(0);
      __builtin_amdgcn_s_setprio(1);
      #pragma unroll
      for (int mi = 0; mi < 2; ++mi)
        #pragma unroll
        for (int n = 0; n < 4; ++n)
          #pragma unroll
          for (int kk = 0; kk < 2; ++kk)
            acc[6+mi][n] = MFMA(afr[mi][kk], bfrag[n][kk], acc[6+mi][n]);
      __builtin_amdgcn_s_setprio(0);
      __builtin_amdgcn_s_barrier();
    }
  }
  #undef SA
  #undef SB

  if (MODE == 0){
    // -------- full-line bf16 scatter epilogue via per-wave LDS bounce (R7) --------
    __syncthreads();
    const int which = (int)(col0 >> 10);
    const int h = (int)((col0 & 1023) >> 6) + wc;
    const float sc = (which == 0) ? 0.125f : 1.0f;
    unsigned short* st = (unsigned short*)lds + wid*8192;
    #pragma unroll
    for (int pass = 0; pass < 2; ++pass){
      #pragma unroll
      for (int mm = 0; mm < 4; ++mm)
        #pragma unroll
        for (int n = 0; n < 4; ++n)
          #pragma unroll
          for (int q2 = 0; q2 < 4; ++q2)
            st[(mm*16 + g*4 + q2)*72 + n*16 + r16] = f2bfbits(acc[pass*4 + mm][n][q2] * sc);
      const long prow0 = row0 + wr*128 + pass*64;
      if (which < 2){
        unsigned short* dst = (which == 0) ? oq : ok2;
        #pragma unroll
        for (int rd = 0; rd < 8; ++rd){
          const int rl = rd*8 + (lane >> 3);
          const int gr = lane & 7;
          uint4 v = *(const uint4*)&st[rl*72 + gr*8];
          const long ii = prow0 + rl;
          const int b_ = (int)(ii >> 12), pos = (int)(ii & 4095);
          *(uint4*)&dst[(((long)b_*16 + h)*4096 + pos)*64 + gr*8] = v;
        }
      } else {
        #pragma unroll
        for (int rd = 0; rd < 8; ++rd){
          const int blk = rd >> 1;
          const int d = (rd & 1)*32 + (lane >> 1);
          const int kkh = lane & 1;
          unsigned short tmp[8];
          #pragma unroll
          for (int j = 0; j < 8; ++j)
            tmp[j] = st[(blk*16 + kkh*8 + j)*72 + d];
          uint4 v;
          v.x = (unsigned int)tmp[0] | ((unsigned int)tmp[1] << 16);
          v.y = (unsigned int)tmp[2] | ((unsigned int)tmp[3] << 16);
          v.z = (unsigned int)tmp[4] | ((unsigned int)tmp[5] << 16);
          v.w = (unsigned int)tmp[6] | ((unsigned int)tmp[7] << 16);
          const long posblk = (prow0 >> 4) + blk;
          const int b_ = (int)(posblk >> 8), blkg = (int)(posblk & 255);
          *(uint4*)&ov[(((long)b_*16 + h)*256 + blkg)*1024 + d*16 + kkh*8] = v;
        }
      }
      __builtin_amdgcn_sched_barrier(0);
    }
  } else {
    // -------- full-line fp32 epilogue via per-wave [16][68] LDS bounce --------
    __syncthreads();
    float* stf = (float*)(lds + wid*4352);     // 16 rows x 68 f32 = 4352 B/wave
    float bi[4];
    #pragma unroll
    for (int n = 0; n < 4; ++n) bi[n] = bias[col0 + wc*64 + n*16 + r16];
    #pragma unroll
    for (int mm = 0; mm < 8; ++mm){
      #pragma unroll
      for (int n = 0; n < 4; ++n)
        #pragma unroll
        for (int q2 = 0; q2 < 4; ++q2)
          stf[(g*4 + q2)*68 + n*16 + r16] = acc[mm][n][q2] + bi[n];
      const long prow0 = row0 + wr*128 + mm*16;
      #pragma unroll
      for (int rr = 0; rr < 4; ++rr){
        const int rowl = (lane >> 4) + rr*4;
        f32x4 v = *(const f32x4*)&stf[rowl*68 + (lane & 15)*4];
        *(f32x4*)&outp[(prow0 + rowl)*1024 + col0 + wc*64 + (lane & 15)*4] = v;
      }
      __builtin_amdgcn_sched_barrier(0);       // reads of stf before next mm's writes
    }
  }
}

// ---------------- hierarchical coarsen, half-compacted outputs (R7) ----------------
__global__ __launch_bounds__(256) void coarsen(
    const unsigned short* __restrict__ q0, const unsigned short* __restrict__ k0,
    const unsigned short* __restrict__ vt0,
    unsigned short* __restrict__ qch, unsigned short* __restrict__ kch,
    unsigned short* __restrict__ vch)
{
  __shared__ float Abuf[128*65];
  __shared__ float Bbuf[64*65];
  const int t = threadIdx.x;
  const int chunk = blockIdx.x;
  const int bh = blockIdx.y;
  const int arr = blockIdx.z;
  if (arr < 2){
    const unsigned short* src = (arr == 0) ? q0 : k0;
    const long sbase = ((long)bh*4096 + (long)chunk*128) * 64;
    #pragma unroll
    for (int it = 0; it < 4; ++it){
      const int idx = it*2048 + t*8;
      uint4 raw = *(const uint4*)(src + sbase + idx);
      float f[8]; unpack8(raw, f);
      const int rowb = idx >> 6, colb = idx & 63;
      #pragma unroll
      for (int j = 0; j < 8; ++j) Abuf[rowb*65 + colb + j] = f[j];
    }
  } else {
    const long sbase = ((long)bh*256 + (long)chunk*8) * 1024;
    #pragma unroll
    for (int it = 0; it < 4; ++it){
      const int flat = it*2048 + t*8;
      const int blk = flat >> 10, rem = flat & 1023;
      const int d = rem >> 4, kk0 = rem & 15;
      uint4 raw = *(const uint4*)(vt0 + sbase + flat);
      float f[8]; unpack8(raw, f);
      #pragma unroll
      for (int j = 0; j < 8; ++j) Abuf[(blk*16 + kk0 + j)*65 + d] = f[j];
    }
  }
  __syncthreads();
  float* cur = Abuf; float* nxt = Bbuf;
  int rows = 128;
  const int Spre[8] = {0, 0, 1024, 1536, 1792, 1920, 1984, 2016};
  for (int l = 1; l <= 7; ++l){
    rows >>= 1;
    const int P = 2048 >> l;
    const long base = (long)Spre[l] * 4096;
    for (int e = t; e < rows*64; e += 256){
      const int p = e >> 6, d = e & 63;
      const float a = cur[(2*p)*65 + d], b2 = cur[(2*p + 1)*65 + d];
      const float val = (arr == 2) ? (a + b2) : 0.5f*(a + b2);
      nxt[p*65 + d] = val;
      const int pl = chunk*rows + p;
      const int cb = pl >> 4, ci = cb >> 1;
      if (arr == 0){
        if (cb & 1) qch[base + ((long)bh*P + ci*16 + (pl & 15))*64 + d] = f2bfbits(val);
      } else if (arr == 1){
        if (!(cb & 1)) kch[base + ((long)bh*P + ci*16 + (pl & 15))*64 + d] = f2bfbits(val);
      } else if (rows < 16){
        if (!(cb & 1)) vch[base + (long)bh*P*64 + ci*1024 + d*16 + (pl & 15)] = f2bfbits(val);
      }
    }
    __syncthreads();
    if (arr == 2 && rows >= 16){
      const int nblk = rows >> 4;
      for (int oe = t; oe < nblk*1024; oe += 256){
        const int bl = oe >> 10, rem = oe & 1023;
        const int cb = chunk*nblk + bl;
        if (cb & 1) continue;
        const int d = rem >> 4, kk = rem & 15;
        vch[base + (long)bh*P*64 + (long)(cb>>1)*1024 + rem] = f2bfbits(nxt[(bl*16 + kk)*65 + d]);
      }
    }
    float* tmp = cur; cur = nxt; nxt = tmp;
  }
}

// ------- fused all-level attention: 4 waves/block, wave-private quadrants (R8, reverted) -------
__global__ __launch_bounds__(256) void attn_fused(
    const unsigned short* __restrict__ q0, const unsigned short* __restrict__ k0,
    const unsigned short* __restrict__ vt0,
    const unsigned short* __restrict__ qch, const unsigned short* __restrict__ kch,
    const unsigned short* __restrict__ vch,
    unsigned short* __restrict__ ybf)
{
  const int lane = threadIdx.x & 63;
  const int w = threadIdx.x >> 6;
  const int B0 = blockIdx.x * 4 + w;   // 0..255 (16-row output block)
  const int bh = blockIdx.y;           // 0..63
  const int b_ = bh >> 4, h = bh & 15;
  const int r = lane & 15, g = lane >> 4;
  __shared__ float accs_all[4][16*64];
  __shared__ float denoms_all[4][16];
  float* accs = accs_all[w];
  float* denoms = denoms_all[w];

  // ---- level 0: causal diagonal 16x16 ----
  {
    const long base = ((long)bh*4096 + (long)B0*16) * 64;
    const bf16x8 ka0 = *(const bf16x8*)(k0 + base + r*64 + g*8);
    const bf16x8 ka1 = *(const bf16x8*)(k0 + base + r*64 + g*8 + 32);
    const bf16x8 qb0 = *(const bf16x8*)(q0 + base + r*64 + g*8);
    const bf16x8 qb1 = *(const bf16x8*)(q0 + base + r*64 + g*8 + 32);
    f32x4 s = {0.f,0.f,0.f,0.f};
    s = MFMA(ka0, qb0, s);
    s = MFMA(ka1, qb1, s);

    float p[4];
    float mx = -3.402823466e38f;
    #pragma unroll
    for (int j = 0; j < 4; ++j){
      const int c = g*4 + j;
      p[j] = (c <= r) ? s[j] : -3.402823466e38f;
      mx = fmaxf(mx, p[j]);
    }
    mx = fmaxf(mx, __shfl_xor(mx, 16));
    mx = fmaxf(mx, __shfl_xor(mx, 32));
    float rs = 0.f;
    #pragma unroll
    for (int j = 0; j < 4; ++j){
      const int c = g*4 + j;
      p[j] = (c <= r) ? __expf(p[j] - mx) : 0.f;
      rs += p[j];
    }
    rs += __shfl_xor(rs, 16);
    rs += __shfl_xor(rs, 32);

    float x16[4], x32[4], x48[4];
    #pragma unroll
    for (int j = 0; j < 4; ++j){
      x16[j] = __shfl_xor(p[j], 16);
      x32[j] = __shfl_xor(p[j], 32);
      x48[j] = __shfl_xor(p[j], 48);
    }
    bf16x8 af;
    #pragma unroll
    for (int j = 0; j < 4; ++j){
      const float lo = (g == 0) ? p[j]   : (g == 1) ? x48[j] : 0.f;
      const float hi = (g == 0) ? x16[j] : (g == 1) ? x32[j] : 0.f;
      af[j]   = (bf16_t)lo;
      af[j+4] = (bf16_t)hi;
    }
    const unsigned short* vt = vt0 + ((long)bh*256 + B0) * 1024;
    #pragma unroll
    for (int nb = 0; nb < 4; ++nb){
      bf16x8 bv;
      #pragma unroll
      for (int j = 0; j < 8; ++j) bv[j] = (bf16_t)0.f;
      if (g < 2) bv = *(const bf16x8*)(vt + (nb*16 + r)*16 + g*8);
      f32x4 y = {0.f,0.f,0.f,0.f};
      y = MFMA(af, bv, y);
      #pragma unroll
      for (int q2 = 0; q2 < 4; ++q2)
        accs[(g*4 + q2)*64 + nb*16 + r] = y[q2];
    }
    if (g == 0) denoms[r] = rs;
  }

  // ---- levels 1..7 ----
  const int Spre[8] = {0, 0, 1024, 1536, 1792, 1920, 1984, 2016};
  for (int l = 1; l <= 7; ++l){
    int nr, lo, cb;
    if (l <= 4){
      nr = 16 >> l;
      lo = (B0 & ((1 << l) - 1)) << (4 - l);
      cb = B0 >> l;
    } else {
      const int m = 1 << (l - 4);
      if ((B0 & (m - 1)) != m - 1) continue;
      const int qrow = ((B0 + 1) >> (l - 4)) - 1;
      cb = qrow >> 4; lo = qrow & 15; nr = 1;
    }
    if (!(cb & 1)) continue;
    const int ci = cb >> 1;
    const int P = 2048 >> l;
    const long base = (long)Spre[l] * 4096;
    const long qb_base = base + ((long)bh*P + ci*16) * 64;
    const long kv_base = base + (long)bh*P*64 + (long)ci*1024;

    const bf16x8 ka0 = *(const bf16x8*)(kch + qb_base + r*64 + g*8);
    const bf16x8 ka1 = *(const bf16x8*)(kch + qb_base + r*64 + g*8 + 32);
    const bf16x8 qb0 = *(const bf16x8*)(qch + qb_base + r*64 + g*8);
    const bf16x8 qb1 = *(const bf16x8*)(qch + qb_base + r*64 + g*8 + 32);
    f32x4 s = {0.f,0.f,0.f,0.f};
    s = MFMA(ka0, qb0, s);
    s = MFMA(ka1, qb1, s);

    float p[4];
    float mx = fmaxf(fmaxf(s[0], s[1]), fmaxf(s[2], s[3]));
    mx = fmaxf(mx, __shfl_xor(mx, 16));
    mx = fmaxf(mx, __shfl_xor(mx, 32));
    float rs = 0.f;
    #pragma unroll
    for (int j = 0; j < 4; ++j){ p[j] = __expf(s[j] - mx); rs += p[j]; }
    rs += __shfl_xor(rs, 16);
    rs += __shfl_xor(rs, 32);

    float x16[4], x32[4], x48[4];
    #pragma unroll
    for (int j = 0; j < 4; ++j){
      x16[j] = __shfl_xor(p[j], 16);
      x32[j] = __shfl_xor(p[j], 32);
      x48[j] = __shfl_xor(p[j], 48);
    }
    bf16x8 af;
    #pragma unroll
    for (int j = 0; j < 4; ++j){
      const float lo2 = (g == 0) ? p[j]   : (g == 1) ? x48[j] : 0.f;
      const float hi2 = (g == 0) ? x16[j] : (g == 1) ? x32[j] : 0.f;
      af[j]   = (bf16_t)lo2;
      af[j+4] = (bf16_t)hi2;
    }
    #pragma unroll
    for (int nb = 0; nb < 4; ++nb){
      bf16x8 bv;
      #pragma unroll
      for (int j = 0; j < 8; ++j) bv[j] = (bf16_t)0.f;
      if (g < 2) bv = *(const bf16x8*)(vch + kv_base + (nb*16 + r)*16 + g*8);
      f32x4 y = {0.f,0.f,0.f,0.f};
      y = MFMA(af, bv, y);
      #pragma unroll
      for (int q2 = 0; q2 < 4; ++q2){
        const int row = g*4 + q2;
        if (row >= lo && row < lo + nr){
          const int ii = (((cb*16 + row + 1) << l) - 1) - (B0 << 4);
          accs[ii*64 + nb*16 + r] += y[q2];
        }
      }
    }
    if (g == 0 && r >= lo && r < lo + nr){
      const int ii = (((cb*16 + r + 1) << l) - 1) - (B0 << 4);
      denoms[ii] += rs;
    }
  }

  // ---- normalize + write bf16 ----
  const int row = lane >> 2, d0 = (lane & 3) * 16;
  const float inv = 1.f / (denoms[row] + 1e-8f);
  unsigned int wv[8];
  #pragma unroll
  for (int j2 = 0; j2 < 8; ++j2){
    const float a = accs[row*64 + d0 + 2*j2]      * inv;
    const float b2 = accs[row*64 + d0 + 2*j2 + 1] * inv;
    wv[j2] = (unsigned int)f2bfbits(a) | ((unsigned int)f2bfbits(b2) << 16);
  }
  uint4* dst = (uint4*)(ybf + ((long)b_*4096 + B0*16 + row)*1024 + h*64 + d0);
  dst[0] = make_uint4(wv[0], wv[1], wv[2], wv[3]);
  dst[1] = make_uint4(wv[4], wv[5], wv[6], wv[7]);
}

extern "C" void kernel_launch(void* const* d_in, const int* in_sizes, int n_in,
                              void* d_out, int out_size, void* d_ws, size_t ws_size,
                              hipStream_t stream){
  const float* x    = (const float*)d_in[0];
  const float* wqkv = (const float*)d_in[1];
  const float* wout = (const float*)d_in[2];
  const float* bout = (const float*)d_in[3];
  float* out = (float*)d_out;
  char* ws = (char*)d_ws;

  unsigned short* wqb = (unsigned short*)(ws + 0L);
  unsigned short* wob = (unsigned short*)(ws + 6291456L);
  unsigned short* xb  = (unsigned short*)(ws + 8388608L);
  unsigned short* q0  = (unsigned short*)(ws + 41943040L);
  unsigned short* k0  = (unsigned short*)(ws + 75497472L);
  unsigned short* vt0 = (unsigned short*)(ws + 109051904L);
  unsigned short* qch = (unsigned short*)(ws + 142606336L);
  unsigned short* kch = (unsigned short*)(ws + 159252480L);
  unsigned short* vch = (unsigned short*)(ws + 175898624L);
  unsigned short* ybf = xb;

  cvt_all<<<2048, 256, 0, stream>>>(x, wqkv, wout, xb, wqb, wob);

  gemm256<0><<<768, 512, 0, stream>>>(xb, wqb, 1024, 12, q0, k0, vt0, nullptr, nullptr);
  coarsen<<<dim3(32,64,3), 256, 0, stream>>>(q0, k0, vt0, qch, kch, vch);
  attn_fused<<<dim3(64,64), 256, 0, stream>>>(q0, k0, vt0, qch, kch, vch, ybf);
  gemm256<1><<<256, 512, 0, stream>>>(ybf, wob, 1024, 4, nullptr, nullptr, nullptr, out, bout);
}